// Round 14
// baseline (451.031 us; speedup 1.0000x reference)
//
#include <hip/hip_runtime.h>
#include <hip/hip_bf16.h>
#include <hip/hip_fp16.h>

#define N_NODES 10000
#define N_EDGES 160000
#define FEAT_W 320
#define CHUNK 32

typedef _Float16 half8 __attribute__((ext_vector_type(8)));
typedef float f32x4 __attribute__((ext_vector_type(4)));

__device__ __forceinline__ float gelu_tanh(float x) {
    float x3 = x * x * x;
    float t = tanhf(0.7978845608028654f * (x + 0.044715f * x3));
    return 0.5f * x * (1.0f + t);
}

// ---------------- Kernel 1: node transforms, 8 nodes/block, fused feat+self -
__global__ __launch_bounds__(320) void node_transform(
    const float* __restrict__ node_input,
    const float* __restrict__ Wa0, const float* __restrict__ Wa1,
    const float* __restrict__ Wb0, const float* __restrict__ Wb1,
    float* __restrict__ feat_tbl, float* __restrict__ self_tbl)
{
    __shared__ __align__(16) float xT[FEAT_W][8];   // 10.24 KB
    const int node0 = blockIdx.x * 8;
    const int t = threadIdx.x;                      // 0..319 = output col
    for (int q = t; q < 640; q += 320) {            // 8 rows x 80 float4
        const int n = q / 80, c4 = q - n * 80;
        const float4 v = ((const float4*)(node_input + (size_t)(node0 + n) * FEAT_W))[c4];
        xT[c4 * 4 + 0][n] = v.x; xT[c4 * 4 + 1][n] = v.y;
        xT[c4 * 4 + 2][n] = v.z; xT[c4 * 4 + 3][n] = v.w;
    }
    __syncthreads();

    float accf[8] = {0,0,0,0,0,0,0,0}, accs[8] = {0,0,0,0,0,0,0,0};
    float scale;
    if (t < 128) {
        for (int v = 0; v < 128; ++v) {
            const float wa = Wa0[v * 128 + t];
            const float wb = Wb0[v * 128 + t];
            const float4 xa = *(const float4*)&xT[v][0];
            const float4 xb = *(const float4*)&xT[v][4];
            accf[0] += xa.x * wa; accf[1] += xa.y * wa; accf[2] += xa.z * wa; accf[3] += xa.w * wa;
            accf[4] += xb.x * wa; accf[5] += xb.y * wa; accf[6] += xb.z * wa; accf[7] += xb.w * wa;
            accs[0] += xa.x * wb; accs[1] += xa.y * wb; accs[2] += xa.z * wb; accs[3] += xa.w * wb;
            accs[4] += xb.x * wb; accs[5] += xb.y * wb; accs[6] += xb.z * wb; accs[7] += xb.w * wb;
        }
        scale = 0.08838834764831845f;               // 1/sqrt(128)
    } else {
        const int r = t - 128, u = r / 3, i = r - 3 * u;
        for (int v = 0; v < 64; ++v) {
            const float wa = Wa1[v * 64 + u];
            const float wb = Wb1[v * 64 + u];
            const int row = 128 + v * 3 + i;
            const float4 xa = *(const float4*)&xT[row][0];
            const float4 xb = *(const float4*)&xT[row][4];
            accf[0] += xa.x * wa; accf[1] += xa.y * wa; accf[2] += xa.z * wa; accf[3] += xa.w * wa;
            accf[4] += xb.x * wa; accf[5] += xb.y * wa; accf[6] += xb.z * wa; accf[7] += xb.w * wa;
            accs[0] += xa.x * wb; accs[1] += xa.y * wb; accs[2] += xa.z * wb; accs[3] += xa.w * wb;
            accs[4] += xb.x * wb; accs[5] += xb.y * wb; accs[6] += xb.z * wb; accs[7] += xb.w * wb;
        }
        scale = 0.125f;                             // 1/sqrt(64)
    }
#pragma unroll
    for (int n = 0; n < 8; ++n) {
        feat_tbl[(size_t)(node0 + n) * FEAT_W + t] = accf[n] * scale;
        self_tbl[(size_t)(node0 + n) * FEAT_W + t] = accs[n] * scale;
    }
}

// ---------------- Kernel 2: per-edge MLP -> h2 (+ degree count fused) -------
__global__ __launch_bounds__(256) void mlp_kernel(
    const float* __restrict__ esa,   // (E,8)
    const float* __restrict__ M1,    // (8,64)
    const float* __restrict__ M2,    // (64,64)
    const int* __restrict__ edge_dst,
    float* __restrict__ h2buf,       // (E,64)
    int* __restrict__ counts)
{
    __shared__ __align__(16) float sh[4][64];
    const int wave = threadIdx.x >> 6;
    const int lane = threadIdx.x & 63;
    const int e = blockIdx.x * 4 + wave;   // N_EDGES % 4 == 0

    if (lane == 0) atomicAdd(&counts[edge_dst[e]], 1);

    const float4 e0 = ((const float4*)(esa + (size_t)e * 8))[0];
    const float4 e1 = ((const float4*)(esa + (size_t)e * 8))[1];
    float h = e0.x * M1[0 * 64 + lane] + e0.y * M1[1 * 64 + lane]
            + e0.z * M1[2 * 64 + lane] + e0.w * M1[3 * 64 + lane]
            + e1.x * M1[4 * 64 + lane] + e1.y * M1[5 * 64 + lane]
            + e1.z * M1[6 * 64 + lane] + e1.w * M1[7 * 64 + lane];
    h = gelu_tanh(h * 0.35355339059327373f);   // 1/sqrt(8)
    sh[wave][lane] = h;
    __syncthreads();

    float h2 = 0.f;
    const float4* shp = (const float4*)sh[wave];
#pragma unroll
    for (int q = 0; q < 16; ++q) {
        const float4 s = shp[q];
        h2 += s.x * M2[(4 * q + 0) * 64 + lane];
        h2 += s.y * M2[(4 * q + 1) * 64 + lane];
        h2 += s.z * M2[(4 * q + 2) * 64 + lane];
        h2 += s.w * M2[(4 * q + 3) * 64 + lane];
    }
    h2 = gelu_tanh(h2 * 0.125f);               // 1/sqrt(64)
    h2buf[(size_t)e * 64 + lane] = h2;
}

// ---------------- CSR build -------------------------------------------------
__global__ __launch_bounds__(1024) void scan_kernel(
    const int* __restrict__ counts, int* __restrict__ offsets, int* __restrict__ cursor)
{
    __shared__ int wsum[16];
    const int wid = threadIdx.x >> 6, lane = threadIdx.x & 63;
    int base = 0;
    for (int c = 0; c < 10; ++c) {            // 10*1024 >= 10000
        const int i = c * 1024 + threadIdx.x;
        const int v = (i < N_NODES) ? counts[i] : 0;
        int x = v;
#pragma unroll
        for (int off = 1; off < 64; off <<= 1) {
            int y = __shfl_up(x, off, 64);
            if (lane >= off) x += y;
        }
        if (lane == 63) wsum[wid] = x;
        __syncthreads();
        if (threadIdx.x < 16) {
            int s = wsum[threadIdx.x];
#pragma unroll
            for (int off = 1; off < 16; off <<= 1) {
                int y = __shfl_up(s, off, 64);
                if ((int)threadIdx.x >= off) s += y;
            }
            wsum[threadIdx.x] = s;
        }
        __syncthreads();
        const int waveoff = (wid == 0) ? 0 : wsum[wid - 1];
        const int excl = base + waveoff + x - v;
        if (i < N_NODES) { offsets[i] = excl; cursor[i] = excl; }
        const int tot = wsum[15];
        __syncthreads();
        base += tot;
    }
    if (threadIdx.x == 0) offsets[N_NODES] = base;
}

// fill: emits CSR-permuted edge id, src, y4
__global__ void fill_kernel(const int* __restrict__ edge_dst,
                            const int* __restrict__ edge_src,
                            const float* __restrict__ edge_attr,
                            int* __restrict__ cursor, int* __restrict__ elist,
                            int* __restrict__ srcs_csr, float* __restrict__ y4csr) {
    int e = blockIdx.x * 256 + threadIdx.x;
    if (e < N_EDGES) {
        int pos = atomicAdd(&cursor[edge_dst[e]], 1);
        elist[pos] = e;
        srcs_csr[pos] = edge_src[e];
        ((float4*)y4csr)[pos] = ((const float4*)edge_attr)[e];
    }
}

// ---------------- Kernel 3: fused gather: MFMA proj + TP + out-GEMM ---------
// 384 threads = 6 waves per block, one block per node. Wave w owns col-tiles
// [w*4, w*4+4) of 24 (cols w*64..w*64+63); B frags in 32 VGPRs (loaded once).
// Per chunk of 32 edges: A frags straight from h2buf rows (guarded), 16 MFMAs
// per wave -> f16 wsh tile -> barrier -> TP (R13-validated mapping) -> z.
// MFMA layouts HW-validated via R12/R13 wproj (passing): A[m=lane&15][k=quad*8+j],
// B[k][n=lane&15], D col=lane&15(=n) row=quad*4+reg(=edge).
__global__ __launch_bounds__(384) void gather_kernel(
    const int* __restrict__ offsets, const int* __restrict__ elist,
    const int* __restrict__ srcs_csr,
    const float* __restrict__ y4csr,
    const float* __restrict__ h2buf,       // (E,64)
    const float* __restrict__ feat_tbl,    // (N,320)
    const float* __restrict__ self_tbl,    // (N,320)
    const float* __restrict__ Wtp0,        // (64,128)
    const float* __restrict__ Wtp1,        // (64,128)
    const float* __restrict__ Wtp2,        // (64,64)
    const float* __restrict__ Wtp3,        // (64,64)
    const float* __restrict__ Wo0,         // (192,128)
    const float* __restrict__ Wo1,         // (192,64)
    float* __restrict__ out)               // (N,320)
{
    __shared__ __align__(16) __half wsh[CHUNK * 384];  // 24 KB
    __shared__ float ys[CHUNK][4];
    __shared__ int   eids[CHUNK];
    __shared__ int   srcs[CHUNK];
    __shared__ float z[768];

    const int node = blockIdx.x;
    const int t = threadIdx.x;             // 0..383
    const int wave = t >> 6;
    const int lane = t & 63;
    const int quad = lane >> 4;
    const int n16 = lane & 15;

    // ---- B fragments for this wave's 4 col-tiles (once per kernel) ----
    half8 bf[4][2];
#pragma unroll
    for (int c = 0; c < 4; ++c) {
        const int col = wave * 64 + c * 16 + n16;
        const float* src; int stride;
        if (col < 128)      { src = Wtp0 + col;         stride = 128; }
        else if (col < 256) { src = Wtp1 + (col - 128); stride = 128; }
        else if (col < 320) { src = Wtp2 + (col - 256); stride = 64;  }
        else                { src = Wtp3 + (col - 320); stride = 64;  }
#pragma unroll
        for (int s = 0; s < 2; ++s)
#pragma unroll
            for (int j = 0; j < 8; ++j)
                bf[c][s][j] = (_Float16)src[(s * 32 + quad * 8 + j) * stride];
    }

    // TP feat index
    int f0;
    if (t < 128)      f0 = t;
    else if (t < 256) f0 = t - 128;
    else if (t < 320) f0 = 128 + 3 * (t - 256);
    else              f0 = 128 + 3 * (t - 320);

    float acc = 0.f, acc3a = 0.f, acc3b = 0.f, acc3c = 0.f;
    const int beg = offsets[node], end = offsets[node + 1];

    for (int cb = beg; cb < end; cb += CHUNK) {
        const int ne = min(CHUNK, end - cb);
        if (t < ne) {
            eids[t] = elist[cb + t];
            srcs[t] = srcs_csr[cb + t];
            ((float4*)ys)[t] = ((const float4*)y4csr)[cb + t];
        }
        __syncthreads();

        // ---- MFMA projection: 2 edge-halves x 4 col-tiles x 2 k-steps ----
#pragma unroll
        for (int g = 0; g < 2; ++g) {                  // edges g*16 .. g*16+15
            const int eidx = g * 16 + n16;             // A row m = n16
            half8 af[2];
            if (eidx < ne) {
                const float* hrow = h2buf + (size_t)eids[eidx] * 64;
#pragma unroll
                for (int s = 0; s < 2; ++s) {
                    const float4 p0 = *(const float4*)(hrow + s * 32 + quad * 8);
                    const float4 p1 = *(const float4*)(hrow + s * 32 + quad * 8 + 4);
                    af[s][0] = (_Float16)p0.x; af[s][1] = (_Float16)p0.y;
                    af[s][2] = (_Float16)p0.z; af[s][3] = (_Float16)p0.w;
                    af[s][4] = (_Float16)p1.x; af[s][5] = (_Float16)p1.y;
                    af[s][6] = (_Float16)p1.z; af[s][7] = (_Float16)p1.w;
                }
            } else {
#pragma unroll
                for (int s = 0; s < 2; ++s)
#pragma unroll
                    for (int j = 0; j < 8; ++j) af[s][j] = (_Float16)0.f;
            }
#pragma unroll
            for (int c = 0; c < 4; ++c) {
                f32x4 a4 = {0.f, 0.f, 0.f, 0.f};
                a4 = __builtin_amdgcn_mfma_f32_16x16x32_f16(af[0], bf[c][0], a4, 0, 0, 0);
                a4 = __builtin_amdgcn_mfma_f32_16x16x32_f16(af[1], bf[c][1], a4, 0, 0, 0);
#pragma unroll
                for (int r = 0; r < 4; ++r) {
                    const int edge = g * 16 + quad * 4 + r;     // D row
                    wsh[edge * 384 + wave * 64 + c * 16 + n16] =
                        (__half)(a4[r] * 0.125f);               // 1/sqrt(64)
                }
            }
        }
        __syncthreads();

        // ---- tensor product accumulate (R13-validated) ----
        if (t < 128) {                       // A: mid0a
            for (int e = 0; e < ne; ++e) {
                const float w = __half2float(wsh[e * 384 + t]);
                const float* fr = feat_tbl + (size_t)srcs[e] * FEAT_W;
                acc += w * fr[f0] * ys[e][0];
            }
        } else if (t < 256) {                // B: mid1a
            for (int e = 0; e < ne; ++e) {
                const float w = __half2float(wsh[e * 384 + t]);
                const float* fr = feat_tbl + (size_t)srcs[e] * FEAT_W;
                const float p = w * fr[f0];
                acc3a += p * ys[e][1];
                acc3b += p * ys[e][2];
                acc3c += p * ys[e][3];
            }
        } else if (t < 320) {                // C: mid1b
            for (int e = 0; e < ne; ++e) {
                const float w = __half2float(wsh[e * 384 + t]);
                const float* fr = feat_tbl + (size_t)srcs[e] * FEAT_W;
                const float p = w * ys[e][0];
                acc3a += p * fr[f0];
                acc3b += p * fr[f0 + 1];
                acc3c += p * fr[f0 + 2];
            }
        } else {                             // D: mid0b
            for (int e = 0; e < ne; ++e) {
                const float w = __half2float(wsh[e * 384 + t]);
                const float* fr = feat_tbl + (size_t)srcs[e] * FEAT_W;
                const float d = fr[f0] * ys[e][1] + fr[f0 + 1] * ys[e][2]
                              + fr[f0 + 2] * ys[e][3];
                acc += w * d;
            }
        }
        __syncthreads();   // before next chunk overwrites LDS
    }

    // ---- write z (proj 1/8 folded; agg 1/sqrt(16) here) ----
    const float sZ = 0.25f;
    if (t < 128) {
        z[t] = acc * sZ;
    } else if (t < 256) {
        const int u = t - 128;
        z[192 + 0 * 192 + u] = acc3a * sZ;
        z[192 + 1 * 192 + u] = acc3b * sZ;
        z[192 + 2 * 192 + u] = acc3c * sZ;
    } else if (t < 320) {
        const int u = t - 256;
        z[192 + 0 * 192 + 128 + u] = acc3a * sZ;
        z[192 + 1 * 192 + 128 + u] = acc3b * sZ;
        z[192 + 2 * 192 + 128 + u] = acc3c * sZ;
    } else {
        z[128 + (t - 320)] = acc * sZ * 0.5773502691896258f;  // mid0b, 1/sqrt(3)
    }
    __syncthreads();

    // ---- output GEMM + rotation combine ----
    const float sA = 0.07216878364870323f;   // 1/sqrt(192)
    const float cR = 0.92387953251128674f;   // cos(pi/8)
    const float sR = 0.38268343236508978f;   // sin(pi/8)

    if (t < 128) {
        float conv = 0.f;
        const float4* z4 = (const float4*)z;
#pragma unroll 8
        for (int q = 0; q < 48; ++q) {
            const float4 zz = z4[q];
            conv += zz.x * Wo0[(4 * q + 0) * 128 + t];
            conv += zz.y * Wo0[(4 * q + 1) * 128 + t];
            conv += zz.z * Wo0[(4 * q + 2) * 128 + t];
            conv += zz.w * Wo0[(4 * q + 3) * 128 + t];
        }
        const float sv = self_tbl[(size_t)node * FEAT_W + t];
        out[(size_t)node * FEAT_W + t] = cR * sv + sR * conv * sA;
    } else if (t < 320) {
        const int idx = t - 128;
        const int i = idx >> 6, u = idx & 63;
        float conv = 0.f;
        const float4* z4 = (const float4*)(z + 192 + i * 192);
#pragma unroll 8
        for (int q = 0; q < 48; ++q) {
            const float4 zz = z4[q];
            conv += zz.x * Wo1[(4 * q + 0) * 64 + u];
            conv += zz.y * Wo1[(4 * q + 1) * 64 + u];
            conv += zz.z * Wo1[(4 * q + 2) * 64 + u];
            conv += zz.w * Wo1[(4 * q + 3) * 64 + u];
        }
        const int col = 128 + u * 3 + i;
        const float sv = self_tbl[(size_t)node * FEAT_W + col];
        out[(size_t)node * FEAT_W + col] = cR * sv + sR * conv * sA;
    }
}

extern "C" void kernel_launch(void* const* d_in, const int* in_sizes, int n_in,
                              void* d_out, int out_size, void* d_ws, size_t ws_size,
                              hipStream_t stream) {
    const float* node_input = (const float*)d_in[0];
    const float* edge_attr  = (const float*)d_in[1];
    const float* esa        = (const float*)d_in[2];
    const float* Wa0  = (const float*)d_in[3];
    const float* Wa1  = (const float*)d_in[4];
    const float* Wb0  = (const float*)d_in[5];
    const float* Wb1  = (const float*)d_in[6];
    const float* M1   = (const float*)d_in[7];
    const float* M2   = (const float*)d_in[8];
    const float* Wtp0 = (const float*)d_in[9];
    const float* Wtp1 = (const float*)d_in[10];
    const float* Wtp2 = (const float*)d_in[11];
    const float* Wtp3 = (const float*)d_in[12];
    const float* Wo0  = (const float*)d_in[13];
    const float* Wo1  = (const float*)d_in[14];
    const int* edge_src = (const int*)d_in[15];
    const int* edge_dst = (const int*)d_in[16];
    float* out = (float*)d_out;

    // ws usage: ~71 MB (wbuf removed)
    float*  feat_tbl = (float*)d_ws;                              // 10000*320
    float*  self_tbl = feat_tbl + (size_t)N_NODES * FEAT_W;       // 10000*320
    float*  h2buf    = self_tbl + (size_t)N_NODES * FEAT_W;       // 160000*64
    float*  y4csr    = h2buf + (size_t)N_EDGES * 64;              // 160000*4
    int*    counts   = (int*)(y4csr + (size_t)N_EDGES * 4);       // 10000
    int*    offsets  = counts + N_NODES;                          // 10001
    int*    cursor   = offsets + N_NODES + 1;                     // 10000
    int*    elist    = cursor + N_NODES;                          // 160000
    int*    srcs_csr = elist + N_EDGES;                           // 160000

    hipMemsetAsync(counts, 0, sizeof(int) * N_NODES, stream);

    node_transform<<<N_NODES / 8, 320, 0, stream>>>(node_input, Wa0, Wa1, Wb0, Wb1,
                                                    feat_tbl, self_tbl);
    mlp_kernel<<<N_EDGES / 4, 256, 0, stream>>>(esa, M1, M2, edge_dst, h2buf, counts);
    scan_kernel<<<1, 1024, 0, stream>>>(counts, offsets, cursor);
    fill_kernel<<<N_EDGES / 256, 256, 0, stream>>>(edge_dst, edge_src, edge_attr,
                                                   cursor, elist, srcs_csr, y4csr);
    gather_kernel<<<N_NODES, 384, 0, stream>>>(offsets, elist, srcs_csr, y4csr,
                                               h2buf, feat_tbl, self_tbl,
                                               Wtp0, Wtp1, Wtp2, Wtp3, Wo0, Wo1, out);
}